// Round 12
// baseline (198.882 us; speedup 1.0000x reference)
//
#include <hip/hip_runtime.h>
#include <hip/hip_bf16.h>

// ---------------------------------------------------------------------------
// STU, last P=16 steps, binary combine tree.
//  - matrix squares ride INSIDE the delta-pipeline launches (validated):
//      g1sq: gemm1 + {C2,D2};  scsq: scatter + {C4,D4};  g2sq: gemm2 + {C8}
//  - r12: the whole tail (reduce_delta + F + G + H + Y) is ONE 64-block
//    kernel with device-scope spin barriers between phases. r11 lesson:
//    4 dependent 8-block launches cost ~10-14 us EACH (launch overhead +
//    MLP-starved 512KB matrix reads); 16K threads per phase fix both.
//  - 5 launches total: prep, g1sq, scsq, g2sq, tailk.
// ---------------------------------------------------------------------------

#define L_SEQ   2048
#define D_OUT   256
#define NK      24
#define PTR     16
#define T0      (L_SEQ - PTR)     // 2032
#define M1      (NK * PTR)        // 384
#define N1      1024
#define K1      2048
#define K2      6912
#define M2P     128
#define N2      256
#define KS1     4
#define KC1     512
#define KS2     36
#define KC2     192
#define NBLK_TAIL 64

#define NB_A1   384
#define NB_BT   512
#define NB_WP   384
#define NB_WM   768
#define NB_LG   192
#define NB_C    1024
#define NB_CT   1024
#define NB_TOT  (NB_A1+NB_BT+NB_WP+NB_WM+NB_LG+NB_C+NB_CT)

typedef unsigned short ushort_t;
typedef unsigned int   uint_t;
typedef __attribute__((ext_vector_type(8))) short short8;
typedef __attribute__((ext_vector_type(4))) float f32x4;

union U16 { uint4 u4; short8 s8; };
union U8x { uint4 u4; ushort_t us[8]; };

__device__ inline ushort_t f2bf(float f) {
    uint_t x = __float_as_uint(f);
    uint_t r = (x + 0x7fffu + ((x >> 16) & 1u)) >> 16;   // RNE
    return (ushort_t)r;
}
__device__ inline float bf2f(ushort_t u) {
    return __uint_as_float(((uint_t)u) << 16);
}
__device__ inline uint_t pack2bf(float a, float b) {
    return (uint_t)f2bf(a) | ((uint_t)f2bf(b) << 16);
}

// --------------------------- fused prep (validated) -------------------------

__global__ __launch_bounds__(256) void prep(
        const float* __restrict__ inputs, const float* __restrict__ eig_vals,
        const float* __restrict__ eig_vecs, const float* __restrict__ m_u,
        const float* __restrict__ m_phi, const float* __restrict__ m_y,
        ushort_t* __restrict__ A1g, ushort_t* __restrict__ BT1,
        ushort_t* __restrict__ WcT, ushort_t* __restrict__ A2s,
        ushort_t* __restrict__ Cmat, ushort_t* __restrict__ Dmat) {
    __shared__ float tile[64][65];
    int bi = blockIdx.x, tid = threadIdx.x;

    if (bi < NB_A1) {
        int idx = bi * 256 + tid;
        int m = idx >> 8, g = idx & 255;
        int k = m >> 4, li = m & 15;
        int t0 = g << 3;
        float sc = sqrtf(sqrtf(eig_vals[k]));
        int sbase = T0 + li - t0;
        U8x v;
#pragma unroll
        for (int j = 0; j < 8; j++) {
            int s = sbase - j;
            float val = (s >= 0) ? sc * eig_vecs[s * NK + k] : 0.f;
            v.us[j] = f2bf(val);
        }
        *reinterpret_cast<uint4*>(A1g + (size_t)m * 2048 + t0) = v.u4;
        return;
    }
    bi -= NB_A1;
    if (bi < NB_BT) {
        int b = bi >> 7, rem = bi & 127;
        int t0 = (rem >> 2) << 6, d0 = (rem & 3) << 6;
#pragma unroll
        for (int i = 0; i < 4; i++) {
            int idx = tid + i * 256;
            int r = idx >> 4, cq = idx & 15;
            float4 v = *reinterpret_cast<const float4*>(
                inputs + ((size_t)b * L_SEQ + t0 + r) * D_OUT + d0 + cq * 4);
            tile[r][cq * 4 + 0] = v.x; tile[r][cq * 4 + 1] = v.y;
            tile[r][cq * 4 + 2] = v.z; tile[r][cq * 4 + 3] = v.w;
        }
        __syncthreads();
        uint_t* dst = reinterpret_cast<uint_t*>(BT1);
#pragma unroll
        for (int i = 0; i < 8; i++) {
            int idx = tid + i * 256;
            int d = idx >> 5, tp = idx & 31;
            uint_t val = pack2bf(tile[2 * tp][d], tile[2 * tp + 1][d]);
            dst[((size_t)(b * 256 + d0 + d)) * (K1 / 2) + (t0 >> 1) + tp] = val;
        }
        return;
    }
    bi -= NB_BT;
    if (bi < NB_WP) {
        int c0 = (bi >> 2) << 6, o0 = (bi & 3) << 6;
#pragma unroll
        for (int i = 0; i < 4; i++) {
            int idx = tid + i * 256;
            int r = idx >> 4, cq = idx & 15;
            float4 v = *reinterpret_cast<const float4*>(
                m_phi + ((size_t)(c0 + r)) * D_OUT + o0 + cq * 4);
            tile[r][cq * 4 + 0] = v.x; tile[r][cq * 4 + 1] = v.y;
            tile[r][cq * 4 + 2] = v.z; tile[r][cq * 4 + 3] = v.w;
        }
        __syncthreads();
        uint_t* dst = reinterpret_cast<uint_t*>(WcT);
#pragma unroll
        for (int i = 0; i < 8; i++) {
            int idx = tid + i * 256;
            int o = idx >> 5, cp = idx & 31;
            uint_t val = pack2bf(tile[2 * cp][o], tile[2 * cp + 1][o]);
            dst[((size_t)(o0 + o)) * (K2 / 2) + (c0 >> 1) + cp] = val;
        }
        return;
    }
    bi -= NB_WP;
    if (bi < NB_WM) {
        int idx = bi * 256 + tid;
        int o = (int)((unsigned)idx / 768u), j = idx - o * 768;
        int kk = j >> 8, i = j & 255;
        WcT[(size_t)o * K2 + 6144 + j] = f2bf(m_u[o * 768 + i * 3 + kk]);
        return;
    }
    bi -= NB_WM;
    if (bi < NB_LG) {
        int idx = bi * 256 + tid;
        int r = (int)((unsigned)idx / 768u), j = idx - r * 768;
        int kk = j >> 8, i = j & 255;
        int b = r >> 4, li = r & 15;
        int l = T0 + li;
        A2s[(size_t)r * K2 + 6144 + j] =
            f2bf(inputs[((size_t)b * L_SEQ + l - kk) * D_OUT + i]);
        return;
    }
    bi -= NB_LG;
    if (bi < NB_C) {
        int idx = bi * 256 + tid;
        int r = idx >> 9, c = idx & 511;
        float val = (r < 256) ? m_y[(size_t)r * 512 + c]
                              : ((c == r - 256) ? 1.f : 0.f);
        Cmat[idx] = f2bf(val);
        return;
    }
    bi -= NB_C;
    {
        int idx = bi * 256 + tid;
        int r = idx >> 9, c = idx & 511;
        float val = (c < 256) ? m_y[(size_t)c * 512 + r]
                              : ((r == c - 256) ? 1.f : 0.f);
        Dmat[idx] = f2bf(val);
    }
}

// ------------------- shared GEMM bodies (device inline) ---------------------

__device__ __forceinline__ void gemm_job(
        ushort_t* As, ushort_t* Bs,
        const ushort_t* __restrict__ A, const ushort_t* __restrict__ BT,
        int bid, int nm, int nn, int K, int kchunk, float* __restrict__ outF) {
    int ks = bid / (nm * nn);
    int rem = bid - ks * (nm * nn);
    int m0 = (rem / nn) << 7;
    int n0 = (rem % nn) << 7;
    int k0 = ks * kchunk;
    int M = nm << 7, N = nn << 7;
    int tid = threadIdx.x;
    int lane = tid & 63, wid = tid >> 6;
    int wm = wid >> 1, wn = wid & 1;
    int r15 = lane & 15, hi4 = lane >> 4;

    f32x4 acc[4][4];
#pragma unroll
    for (int m = 0; m < 4; m++)
#pragma unroll
        for (int n = 0; n < 4; n++) acc[m][n] = (f32x4){0.f, 0.f, 0.f, 0.f};

    for (int kt = k0; kt < k0 + kchunk; kt += 64) {
#pragma unroll
        for (int i = 0; i < 4; i++) {
            int c = tid + i * 256;
            int row = c >> 3, kg = c & 7;
            uint4 va = *reinterpret_cast<const uint4*>(A + (size_t)(m0 + row) * K + kt + kg * 8);
            *reinterpret_cast<uint4*>(&As[row * 64 + ((kg ^ (row & 7)) << 3)]) = va;
            uint4 vb = *reinterpret_cast<const uint4*>(BT + (size_t)(n0 + row) * K + kt + kg * 8);
            *reinterpret_cast<uint4*>(&Bs[row * 64 + ((kg ^ (row & 7)) << 3)]) = vb;
        }
        __syncthreads();
#pragma unroll
        for (int kk = 0; kk < 2; kk++) {
            short8 af[4], bfr[4];
            int chunk = kk * 4 + hi4;
#pragma unroll
            for (int m = 0; m < 4; m++) {
                int row = wm * 64 + m * 16 + r15;
                U16 u; u.u4 = *reinterpret_cast<const uint4*>(&As[row * 64 + ((chunk ^ (row & 7)) << 3)]);
                af[m] = u.s8;
            }
#pragma unroll
            for (int n = 0; n < 4; n++) {
                int row = wn * 64 + n * 16 + r15;
                U16 u; u.u4 = *reinterpret_cast<const uint4*>(&Bs[row * 64 + ((chunk ^ (row & 7)) << 3)]);
                bfr[n] = u.s8;
            }
#pragma unroll
            for (int m = 0; m < 4; m++)
#pragma unroll
                for (int n = 0; n < 4; n++)
                    acc[m][n] = __builtin_amdgcn_mfma_f32_16x16x32_bf16(af[m], bfr[n], acc[m][n], 0, 0, 0);
        }
        __syncthreads();
    }
#pragma unroll
    for (int m = 0; m < 4; m++)
#pragma unroll
        for (int n = 0; n < 4; n++)
#pragma unroll
            for (int r = 0; r < 4; r++) {
                int gm = m0 + wm * 64 + m * 16 + hi4 * 4 + r;
                int gn = n0 + wn * 64 + n * 16 + r15;
                outF[(size_t)ks * M * N + (size_t)gm * N + gn] = acc[m][n][r];
            }
}

// 512x512x512 square: O = A * BT^T, bf16 out, coalesced rows
__device__ __forceinline__ void sq_job(
        ushort_t* As, ushort_t* Bs,
        const ushort_t* __restrict__ A, const ushort_t* __restrict__ BT,
        ushort_t* __restrict__ O, int local) {
    int m0 = (local >> 2) << 7, n0 = (local & 3) << 7;
    int tid = threadIdx.x;
    int lane = tid & 63, wid = tid >> 6;
    int wm = wid >> 1, wn = wid & 1;
    int r15 = lane & 15, hi4 = lane >> 4;

    f32x4 acc[4][4];
#pragma unroll
    for (int m = 0; m < 4; m++)
#pragma unroll
        for (int n = 0; n < 4; n++) acc[m][n] = (f32x4){0.f, 0.f, 0.f, 0.f};

    for (int kt = 0; kt < 512; kt += 64) {
#pragma unroll
        for (int i = 0; i < 4; i++) {
            int c = tid + i * 256;
            int row = c >> 3, kg = c & 7;
            uint4 va = *reinterpret_cast<const uint4*>(A + (size_t)(m0 + row) * 512 + kt + kg * 8);
            *reinterpret_cast<uint4*>(&As[row * 64 + ((kg ^ (row & 7)) << 3)]) = va;
            uint4 vb = *reinterpret_cast<const uint4*>(BT + (size_t)(n0 + row) * 512 + kt + kg * 8);
            *reinterpret_cast<uint4*>(&Bs[row * 64 + ((kg ^ (row & 7)) << 3)]) = vb;
        }
        __syncthreads();
#pragma unroll
        for (int kk = 0; kk < 2; kk++) {
            short8 af[4], bfr[4];
            int chunk = kk * 4 + hi4;
#pragma unroll
            for (int m = 0; m < 4; m++) {
                int row = wm * 64 + m * 16 + r15;
                U16 u; u.u4 = *reinterpret_cast<const uint4*>(&As[row * 64 + ((chunk ^ (row & 7)) << 3)]);
                af[m] = u.s8;
            }
#pragma unroll
            for (int n = 0; n < 4; n++) {
                int row = wn * 64 + n * 16 + r15;
                U16 u; u.u4 = *reinterpret_cast<const uint4*>(&Bs[row * 64 + ((chunk ^ (row & 7)) << 3)]);
                bfr[n] = u.s8;
            }
#pragma unroll
            for (int m = 0; m < 4; m++)
#pragma unroll
                for (int n = 0; n < 4; n++)
                    acc[m][n] = __builtin_amdgcn_mfma_f32_16x16x32_bf16(af[m], bfr[n], acc[m][n], 0, 0, 0);
        }
        __syncthreads();
    }
#pragma unroll
    for (int m = 0; m < 4; m++)
#pragma unroll
        for (int n = 0; n < 4; n++)
#pragma unroll
            for (int r = 0; r < 4; r++) {
                int gm = m0 + wm * 64 + m * 16 + hi4 * 4 + r;
                int gn = n0 + wn * 64 + n * 16 + r15;
                O[(size_t)gm * 512 + gn] = f2bf(acc[m][n][r]);
            }
}

// --------------------------- fused launch kernels ---------------------------

__global__ __launch_bounds__(256) void g1sq(
        const ushort_t* __restrict__ A1g, const ushort_t* __restrict__ BT1,
        float* __restrict__ part1,
        const ushort_t* __restrict__ Cm, const ushort_t* __restrict__ Dm,
        ushort_t* __restrict__ C2, ushort_t* __restrict__ D2) {
    __shared__ __align__(16) ushort_t As[128 * 64];
    __shared__ __align__(16) ushort_t Bs[128 * 64];
    int bid = blockIdx.x;
    if (bid < 96) { gemm_job(As, Bs, A1g, BT1, bid, 3, 8, K1, KC1, part1); return; }
    int sb = bid - 96;
    if ((sb >> 4) == 0) sq_job(As, Bs, Cm, Dm, C2, sb & 15);
    else                sq_job(As, Bs, Dm, Cm, D2, sb & 15);
}

__global__ __launch_bounds__(256) void scsq(
        const float* __restrict__ part1, ushort_t* __restrict__ A2s,
        const ushort_t* __restrict__ C2, const ushort_t* __restrict__ D2,
        ushort_t* __restrict__ C4, ushort_t* __restrict__ D4) {
    __shared__ __align__(16) ushort_t As[128 * 64];
    __shared__ __align__(16) ushort_t Bs[128 * 64];
    int bid = blockIdx.x, tid = threadIdx.x;
    if (bid < 1536) {
        int idx = bid * 256 + tid;
        float s = 0.f;
#pragma unroll
        for (int ks = 0; ks < KS1; ks++) s += part1[(size_t)ks * (M1 * N1) + idx];
        int gm = idx >> 10, gn = idx & 1023;
        int k = gm >> 4, li = gm & 15;
        int b = gn >> 8, d = gn & 255;
        A2s[(size_t)(b * PTR + li) * K2 + k * 256 + d] = f2bf(s);
        return;
    }
    int sb = bid - 1536;
    if ((sb >> 4) == 0) sq_job(As, Bs, C2, D2, C4, sb & 15);
    else                sq_job(As, Bs, D2, C2, D4, sb & 15);
}

// gemm2 (72) + C8 (16); also zeroes the tail spin-barrier vars each call.
__global__ __launch_bounds__(256) void g2sq(
        const ushort_t* __restrict__ A2s, const ushort_t* __restrict__ WcT,
        float* __restrict__ part2,
        const ushort_t* __restrict__ C4, const ushort_t* __restrict__ D4,
        ushort_t* __restrict__ C8, uint_t* __restrict__ bar) {
    __shared__ __align__(16) ushort_t As[128 * 64];
    __shared__ __align__(16) ushort_t Bs[128 * 64];
    int bid = blockIdx.x;
    if (bid == 0 && threadIdx.x == 0) { bar[0] = 0u; bar[1] = 0u; }
    if (bid < 72) { gemm_job(As, Bs, A2s, WcT, bid, 1, 2, K2, KC2, part2); return; }
    sq_job(As, Bs, C4, D4, C8, (bid - 72) & 15);
}

// --------------------------- tail megakernel --------------------------------
// 64 blocks x 256 thr, device-scope sense-reversing barrier between phases.
// phase0: E = reduce(part2)  ->  F = C*E-pairs  ->  G = C2*F-pairs
//      -> H = C4*G-pairs     ->  y = top256(C8*H-pairs)

__device__ __forceinline__ void gsync(uint_t* bar) {
    __syncthreads();
    __threadfence();
    if (threadIdx.x == 0) {
        uint_t g = atomicAdd(&bar[1], 0u);
        if (atomicAdd(&bar[0], 1u) == NBLK_TAIL - 1) {
            atomicExch(&bar[0], 0u);
            __threadfence();
            atomicAdd(&bar[1], 1u);
        } else {
            while (atomicAdd(&bar[1], 0u) == g) { __builtin_amdgcn_s_sleep(2); }
        }
    }
    __syncthreads();
    __threadfence();
}

// dot of C row-slice with hi+lo vector rows (vectorized bf16x8 loads)
__device__ __forceinline__ float dotrow(const ushort_t* __restrict__ Crow,
                                        const ushort_t* __restrict__ Ah,
                                        const ushort_t* __restrict__ Al,
                                        int kin) {
    float acc = 0.f;
    for (int k = 0; k < kin; k += 16) {
        U8x c0, c1, a0, a1, l0, l1;
        c0.u4 = *reinterpret_cast<const uint4*>(Crow + k);
        c1.u4 = *reinterpret_cast<const uint4*>(Crow + k + 8);
        a0.u4 = *reinterpret_cast<const uint4*>(Ah + k);
        a1.u4 = *reinterpret_cast<const uint4*>(Ah + k + 8);
        l0.u4 = *reinterpret_cast<const uint4*>(Al + k);
        l1.u4 = *reinterpret_cast<const uint4*>(Al + k + 8);
#pragma unroll
        for (int j = 0; j < 8; j++) {
            float cv = bf2f(c0.us[j]);
            acc += cv * (bf2f(a0.us[j]) + bf2f(l0.us[j]));
        }
#pragma unroll
        for (int j = 0; j < 8; j++) {
            float cv = bf2f(c1.us[j]);
            acc += cv * (bf2f(a1.us[j]) + bf2f(l1.us[j]));
        }
    }
    return acc;
}

__global__ __launch_bounds__(256) void tailk(
        const float* __restrict__ part2,
        const ushort_t* __restrict__ Cm, const ushort_t* __restrict__ C2,
        const ushort_t* __restrict__ C4, const ushort_t* __restrict__ C8,
        ushort_t* __restrict__ Eh, ushort_t* __restrict__ El,
        ushort_t* __restrict__ Fh, ushort_t* __restrict__ Fl,
        ushort_t* __restrict__ Gh, ushort_t* __restrict__ Gl,
        ushort_t* __restrict__ Hh, ushort_t* __restrict__ Hl,
        float* __restrict__ out, uint_t* __restrict__ bar) {
    int gtid = blockIdx.x * 256 + threadIdx.x;       // < 16384

    // phase 0: E[v][i] (64 x 256), hi/lo
    {
        float s = 0.f;
#pragma unroll
        for (int ks = 0; ks < KS2; ks++) s += part2[(size_t)ks * (M2P * N2) + gtid];
        ushort_t h = f2bf(s);
        Eh[gtid] = h; El[gtid] = f2bf(s - bf2f(h));
    }
    gsync(bar);

    // phase F: 32 vouts x 512 n (kin=256, ninb=16, nbsh=3, Cp=C)
    {
        int vout = gtid >> 9, n = gtid & 511;
        int b2 = vout >> 3, k2 = vout & 7;
        int Arow = b2 * 16 + 2 * k2;
        float val = dotrow(Cm + (size_t)n * 512, Eh + (size_t)Arow * 256,
                           El + (size_t)Arow * 256, 256);
        if (n < 256)
            val += bf2f(Eh[(size_t)(Arow + 1) * 256 + n]) +
                   bf2f(El[(size_t)(Arow + 1) * 256 + n]);
        ushort_t h = f2bf(val);
        Fh[gtid] = h; Fl[gtid] = f2bf(val - bf2f(h));
    }
    gsync(bar);

    // phase G: 16 vouts x 512 n (kin=512, ninb=8, nbsh=2, Cp=C2)
    if (gtid < 8192) {
        int vout = gtid >> 9, n = gtid & 511;
        int b2 = vout >> 2, k2 = vout & 3;
        int Arow = b2 * 8 + 2 * k2;
        float val = dotrow(C2 + (size_t)n * 512, Fh + (size_t)Arow * 512,
                           Fl + (size_t)Arow * 512, 512);
        val += bf2f(Fh[(size_t)(Arow + 1) * 512 + n]) +
               bf2f(Fl[(size_t)(Arow + 1) * 512 + n]);
        ushort_t h = f2bf(val);
        Gh[gtid] = h; Gl[gtid] = f2bf(val - bf2f(h));
    }
    gsync(bar);

    // phase H: 8 vouts x 512 n (kin=512, ninb=4, nbsh=1, Cp=C4)
    if (gtid < 4096) {
        int vout = gtid >> 9, n = gtid & 511;
        int b2 = vout >> 1, k2 = vout & 1;
        int Arow = b2 * 4 + 2 * k2;
        float val = dotrow(C4 + (size_t)n * 512, Gh + (size_t)Arow * 512,
                           Gl + (size_t)Arow * 512, 512);
        val += bf2f(Gh[(size_t)(Arow + 1) * 512 + n]) +
               bf2f(Gl[(size_t)(Arow + 1) * 512 + n]);
        ushort_t h = f2bf(val);
        Hh[gtid] = h; Hl[gtid] = f2bf(val - bf2f(h));
    }
    gsync(bar);

    // phase Y: 4 batches x 256 n (Cp=C8, top-256 only)
    if (gtid < 1024) {
        int b2 = gtid >> 8, n = gtid & 255;
        int Arow = b2 * 2;
        float val = dotrow(C8 + (size_t)n * 512, Hh + (size_t)Arow * 512,
                           Hl + (size_t)Arow * 512, 512);
        val += bf2f(Hh[(size_t)(Arow + 1) * 512 + n]) +
               bf2f(Hl[(size_t)(Arow + 1) * 512 + n]);
        out[gtid] = val;
    }
}

// --------------------------- launch ----------------------------------------

extern "C" void kernel_launch(void* const* d_in, const int* in_sizes, int n_in,
                              void* d_out, int out_size, void* d_ws, size_t ws_size,
                              hipStream_t stream) {
    const float* inputs   = (const float*)d_in[0];
    const float* eig_vals = (const float*)d_in[1];
    const float* eig_vecs = (const float*)d_in[2];
    const float* m_u      = (const float*)d_in[3];
    const float* m_phi    = (const float*)d_in[4];
    const float* m_y      = (const float*)d_in[5];
    float* out = (float*)d_out;
    char* ws = (char*)d_ws;

    ushort_t* A1g   = (ushort_t*)(ws);               // 1572864
    ushort_t* BT1   = (ushort_t*)(ws + 1572864);     // 4194304
    ushort_t* WcT   = (ushort_t*)(ws + 5767168);     // 3538944
    ushort_t* A2s   = (ushort_t*)(ws + 9306112);     // 1769472
    float*    part1 = (float*)   (ws + 11075584);    // 6291456
    float*    part2 = (float*)   (ws + 17367040);    // 4718592
    ushort_t* Eh    = (ushort_t*)(ws + 22085632);    // 32768
    ushort_t* El    = (ushort_t*)(ws + 22118400);    // 32768
    ushort_t* Cmat  = (ushort_t*)(ws + 22151168);    // 524288
    ushort_t* Dmat  = (ushort_t*)(ws + 22675456);    // 524288
    ushort_t* C2    = (ushort_t*)(ws + 23199744);    // 524288
    ushort_t* D2    = (ushort_t*)(ws + 23724032);    // 524288
    ushort_t* C4    = (ushort_t*)(ws + 24248320);    // 524288
    ushort_t* D4    = (ushort_t*)(ws + 24772608);    // 524288
    ushort_t* C8    = (ushort_t*)(ws + 25296896);    // 524288
    ushort_t* Fh    = (ushort_t*)(ws + 25821184);    // 32768
    ushort_t* Fl    = (ushort_t*)(ws + 25853952);    // 32768
    ushort_t* Gh    = (ushort_t*)(ws + 25886720);    // 16384
    ushort_t* Gl    = (ushort_t*)(ws + 25903104);    // 16384
    ushort_t* Hh    = (ushort_t*)(ws + 25919488);    // 8192
    ushort_t* Hl    = (ushort_t*)(ws + 25927680);    // 8192
    uint_t*   bar   = (uint_t*)  (ws + 25935872);    // 8
                                                     // end 25935880

    hipLaunchKernelGGL(prep, dim3(NB_TOT), dim3(256), 0, stream,
                       inputs, eig_vals, eig_vecs, m_u, m_phi, m_y,
                       A1g, BT1, WcT, A2s, Cmat, Dmat);

    hipLaunchKernelGGL(g1sq, dim3(96 + 32), dim3(256), 0, stream,
                       A1g, BT1, part1, Cmat, Dmat, C2, D2);

    hipLaunchKernelGGL(scsq, dim3(1536 + 32), dim3(256), 0, stream,
                       part1, A2s, C2, D2, C4, D4);

    hipLaunchKernelGGL(g2sq, dim3(72 + 16), dim3(256), 0, stream,
                       A2s, WcT, part2, C4, D4, C8, bar);

    hipLaunchKernelGGL(tailk, dim3(NBLK_TAIL), dim3(256), 0, stream,
                       part2, Cmat, C2, C4, C8,
                       Eh, El, Fh, Fl, Gh, Gl, Hh, Hl, out, bar);
}

// Round 13
// 156.974 us; speedup vs baseline: 1.2670x; 1.2670x over previous
//
#include <hip/hip_runtime.h>
#include <hip/hip_bf16.h>

// ---------------------------------------------------------------------------
// STU, last P=16 steps, binary combine tree.
// r13: 4 launches total.
//   prep : builders (A1 Toeplitz, BT1/WcT transposes, u-lags, C, D=C^T)
//   g1sq : gemm1 (x_tilde partials, split-K 4) + {C2=C*C, D2=D*D}
//   g2sq : gemm2 with INLINE part1-reduce A-staging (scatter launch deleted)
//          + {C4=C2*C2}  (C8 deleted: Y uses C4 twice via associativity)
//   tailk: E -> F -> G -> H -> W=C4*h0 -> y=C4*W+h1, 64 blocks, 5 device
//          barriers. r12 lesson: RMW-poll spin = 37us/barrier convoy; fixed
//          by arrive-with-RMW + poll-with-atomic-LOAD, one counter/phase.
// ---------------------------------------------------------------------------

#define L_SEQ   2048
#define D_OUT   256
#define NK      24
#define PTR     16
#define T0      (L_SEQ - PTR)     // 2032
#define M1      (NK * PTR)        // 384
#define N1      1024
#define K1      2048
#define K2      6912
#define M2P     128
#define N2      256
#define KS1     4
#define KC1     512
#define KS2     36
#define KC2     192
#define NBLK_TAIL 64

#define NB_A1   384
#define NB_BT   512
#define NB_WP   384
#define NB_WM   768
#define NB_LG   192
#define NB_C    1024
#define NB_CT   1024
#define NB_TOT  (NB_A1+NB_BT+NB_WP+NB_WM+NB_LG+NB_C+NB_CT)

typedef unsigned short ushort_t;
typedef unsigned int   uint_t;
typedef __attribute__((ext_vector_type(8))) short short8;
typedef __attribute__((ext_vector_type(4))) float f32x4;

union U16 { uint4 u4; short8 s8; };
union U8x { uint4 u4; ushort_t us[8]; };

__device__ inline ushort_t f2bf(float f) {
    uint_t x = __float_as_uint(f);
    uint_t r = (x + 0x7fffu + ((x >> 16) & 1u)) >> 16;   // RNE
    return (ushort_t)r;
}
__device__ inline float bf2f(ushort_t u) {
    return __uint_as_float(((uint_t)u) << 16);
}
__device__ inline uint_t pack2bf(float a, float b) {
    return (uint_t)f2bf(a) | ((uint_t)f2bf(b) << 16);
}

// --------------------------- fused prep (validated) -------------------------

__global__ __launch_bounds__(256) void prep(
        const float* __restrict__ inputs, const float* __restrict__ eig_vals,
        const float* __restrict__ eig_vecs, const float* __restrict__ m_u,
        const float* __restrict__ m_phi, const float* __restrict__ m_y,
        ushort_t* __restrict__ A1g, ushort_t* __restrict__ BT1,
        ushort_t* __restrict__ WcT, ushort_t* __restrict__ A2s,
        ushort_t* __restrict__ Cmat, ushort_t* __restrict__ Dmat) {
    __shared__ float tile[64][65];
    int bi = blockIdx.x, tid = threadIdx.x;

    if (bi < NB_A1) {
        int idx = bi * 256 + tid;
        int m = idx >> 8, g = idx & 255;
        int k = m >> 4, li = m & 15;
        int t0 = g << 3;
        float sc = sqrtf(sqrtf(eig_vals[k]));
        int sbase = T0 + li - t0;
        U8x v;
#pragma unroll
        for (int j = 0; j < 8; j++) {
            int s = sbase - j;
            float val = (s >= 0) ? sc * eig_vecs[s * NK + k] : 0.f;
            v.us[j] = f2bf(val);
        }
        *reinterpret_cast<uint4*>(A1g + (size_t)m * 2048 + t0) = v.u4;
        return;
    }
    bi -= NB_A1;
    if (bi < NB_BT) {
        int b = bi >> 7, rem = bi & 127;
        int t0 = (rem >> 2) << 6, d0 = (rem & 3) << 6;
#pragma unroll
        for (int i = 0; i < 4; i++) {
            int idx = tid + i * 256;
            int r = idx >> 4, cq = idx & 15;
            float4 v = *reinterpret_cast<const float4*>(
                inputs + ((size_t)b * L_SEQ + t0 + r) * D_OUT + d0 + cq * 4);
            tile[r][cq * 4 + 0] = v.x; tile[r][cq * 4 + 1] = v.y;
            tile[r][cq * 4 + 2] = v.z; tile[r][cq * 4 + 3] = v.w;
        }
        __syncthreads();
        uint_t* dst = reinterpret_cast<uint_t*>(BT1);
#pragma unroll
        for (int i = 0; i < 8; i++) {
            int idx = tid + i * 256;
            int d = idx >> 5, tp = idx & 31;
            uint_t val = pack2bf(tile[2 * tp][d], tile[2 * tp + 1][d]);
            dst[((size_t)(b * 256 + d0 + d)) * (K1 / 2) + (t0 >> 1) + tp] = val;
        }
        return;
    }
    bi -= NB_BT;
    if (bi < NB_WP) {
        int c0 = (bi >> 2) << 6, o0 = (bi & 3) << 6;
#pragma unroll
        for (int i = 0; i < 4; i++) {
            int idx = tid + i * 256;
            int r = idx >> 4, cq = idx & 15;
            float4 v = *reinterpret_cast<const float4*>(
                m_phi + ((size_t)(c0 + r)) * D_OUT + o0 + cq * 4);
            tile[r][cq * 4 + 0] = v.x; tile[r][cq * 4 + 1] = v.y;
            tile[r][cq * 4 + 2] = v.z; tile[r][cq * 4 + 3] = v.w;
        }
        __syncthreads();
        uint_t* dst = reinterpret_cast<uint_t*>(WcT);
#pragma unroll
        for (int i = 0; i < 8; i++) {
            int idx = tid + i * 256;
            int o = idx >> 5, cp = idx & 31;
            uint_t val = pack2bf(tile[2 * cp][o], tile[2 * cp + 1][o]);
            dst[((size_t)(o0 + o)) * (K2 / 2) + (c0 >> 1) + cp] = val;
        }
        return;
    }
    bi -= NB_WP;
    if (bi < NB_WM) {
        int idx = bi * 256 + tid;
        int o = (int)((unsigned)idx / 768u), j = idx - o * 768;
        int kk = j >> 8, i = j & 255;
        WcT[(size_t)o * K2 + 6144 + j] = f2bf(m_u[o * 768 + i * 3 + kk]);
        return;
    }
    bi -= NB_WM;
    if (bi < NB_LG) {
        int idx = bi * 256 + tid;
        int r = (int)((unsigned)idx / 768u), j = idx - r * 768;
        int kk = j >> 8, i = j & 255;
        int b = r >> 4, li = r & 15;
        int l = T0 + li;
        A2s[(size_t)r * K2 + 6144 + j] =
            f2bf(inputs[((size_t)b * L_SEQ + l - kk) * D_OUT + i]);
        return;
    }
    bi -= NB_LG;
    if (bi < NB_C) {
        int idx = bi * 256 + tid;
        int r = idx >> 9, c = idx & 511;
        float val = (r < 256) ? m_y[(size_t)r * 512 + c]
                              : ((c == r - 256) ? 1.f : 0.f);
        Cmat[idx] = f2bf(val);
        return;
    }
    bi -= NB_C;
    {
        int idx = bi * 256 + tid;
        int r = idx >> 9, c = idx & 511;
        float val = (c < 256) ? m_y[(size_t)c * 512 + r]
                              : ((r == c - 256) ? 1.f : 0.f);
        Dmat[idx] = f2bf(val);
    }
}

// ------------------- shared GEMM bodies (device inline) ---------------------

__device__ __forceinline__ void gemm_job(
        ushort_t* As, ushort_t* Bs,
        const ushort_t* __restrict__ A, const ushort_t* __restrict__ BT,
        int bid, int nm, int nn, int K, int kchunk, float* __restrict__ outF) {
    int ks = bid / (nm * nn);
    int rem = bid - ks * (nm * nn);
    int m0 = (rem / nn) << 7;
    int n0 = (rem % nn) << 7;
    int k0 = ks * kchunk;
    int M = nm << 7, N = nn << 7;
    int tid = threadIdx.x;
    int lane = tid & 63, wid = tid >> 6;
    int wm = wid >> 1, wn = wid & 1;
    int r15 = lane & 15, hi4 = lane >> 4;

    f32x4 acc[4][4];
#pragma unroll
    for (int m = 0; m < 4; m++)
#pragma unroll
        for (int n = 0; n < 4; n++) acc[m][n] = (f32x4){0.f, 0.f, 0.f, 0.f};

    for (int kt = k0; kt < k0 + kchunk; kt += 64) {
#pragma unroll
        for (int i = 0; i < 4; i++) {
            int c = tid + i * 256;
            int row = c >> 3, kg = c & 7;
            uint4 va = *reinterpret_cast<const uint4*>(A + (size_t)(m0 + row) * K + kt + kg * 8);
            *reinterpret_cast<uint4*>(&As[row * 64 + ((kg ^ (row & 7)) << 3)]) = va;
            uint4 vb = *reinterpret_cast<const uint4*>(BT + (size_t)(n0 + row) * K + kt + kg * 8);
            *reinterpret_cast<uint4*>(&Bs[row * 64 + ((kg ^ (row & 7)) << 3)]) = vb;
        }
        __syncthreads();
#pragma unroll
        for (int kk = 0; kk < 2; kk++) {
            short8 af[4], bfr[4];
            int chunk = kk * 4 + hi4;
#pragma unroll
            for (int m = 0; m < 4; m++) {
                int row = wm * 64 + m * 16 + r15;
                U16 u; u.u4 = *reinterpret_cast<const uint4*>(&As[row * 64 + ((chunk ^ (row & 7)) << 3)]);
                af[m] = u.s8;
            }
#pragma unroll
            for (int n = 0; n < 4; n++) {
                int row = wn * 64 + n * 16 + r15;
                U16 u; u.u4 = *reinterpret_cast<const uint4*>(&Bs[row * 64 + ((chunk ^ (row & 7)) << 3)]);
                bfr[n] = u.s8;
            }
#pragma unroll
            for (int m = 0; m < 4; m++)
#pragma unroll
                for (int n = 0; n < 4; n++)
                    acc[m][n] = __builtin_amdgcn_mfma_f32_16x16x32_bf16(af[m], bfr[n], acc[m][n], 0, 0, 0);
        }
        __syncthreads();
    }
#pragma unroll
    for (int m = 0; m < 4; m++)
#pragma unroll
        for (int n = 0; n < 4; n++)
#pragma unroll
            for (int r = 0; r < 4; r++) {
                int gm = m0 + wm * 64 + m * 16 + hi4 * 4 + r;
                int gn = n0 + wn * 64 + n * 16 + r15;
                outF[(size_t)ks * M * N + (size_t)gm * N + gn] = acc[m][n][r];
            }
}

// gemm2 with inline part1-reduce A-staging (x_tilde cols) + A2s lag cols
__device__ __forceinline__ void gemm2_job(
        ushort_t* As, ushort_t* Bs,
        const float* __restrict__ part1, const ushort_t* __restrict__ A2lag,
        const ushort_t* __restrict__ BT, int bid, float* __restrict__ outF) {
    int ks = bid >> 1;
    int n0 = (bid & 1) << 7;
    int k0 = ks * KC2;
    int tid = threadIdx.x;
    int lane = tid & 63, wid = tid >> 6;
    int wm = wid >> 1, wn = wid & 1;
    int r15 = lane & 15, hi4 = lane >> 4;

    f32x4 acc[4][4];
#pragma unroll
    for (int m = 0; m < 4; m++)
#pragma unroll
        for (int n = 0; n < 4; n++) acc[m][n] = (f32x4){0.f, 0.f, 0.f, 0.f};

    for (int kt = k0; kt < k0 + KC2; kt += 64) {
#pragma unroll
        for (int i = 0; i < 4; i++) {
            int c = tid + i * 256;
            int row = c >> 3, kg = c & 7;
            int col = kt + kg * 8;
            uint4 va;
            if (col < 6144) {
                if (row < 64) {
                    int gm = (col >> 8) * 16 + (row & 15);
                    int gn = ((row >> 4) << 8) + (col & 255);
                    const float* p = part1 + (size_t)gm * 1024 + gn;
                    float4 s0 = *reinterpret_cast<const float4*>(p);
                    float4 s1 = *reinterpret_cast<const float4*>(p + 4);
#pragma unroll
                    for (int q = 1; q < KS1; q++) {
                        const float* pq = p + (size_t)q * (M1 * N1);
                        float4 a0 = *reinterpret_cast<const float4*>(pq);
                        float4 a1 = *reinterpret_cast<const float4*>(pq + 4);
                        s0.x += a0.x; s0.y += a0.y; s0.z += a0.z; s0.w += a0.w;
                        s1.x += a1.x; s1.y += a1.y; s1.z += a1.z; s1.w += a1.w;
                    }
                    va.x = pack2bf(s0.x, s0.y); va.y = pack2bf(s0.z, s0.w);
                    va.z = pack2bf(s1.x, s1.y); va.w = pack2bf(s1.z, s1.w);
                } else {
                    va.x = 0u; va.y = 0u; va.z = 0u; va.w = 0u;
                }
            } else {
                va = *reinterpret_cast<const uint4*>(A2lag + (size_t)row * K2 + col);
            }
            *reinterpret_cast<uint4*>(&As[row * 64 + ((kg ^ (row & 7)) << 3)]) = va;
            uint4 vb = *reinterpret_cast<const uint4*>(BT + (size_t)(n0 + row) * K2 + kt + kg * 8);
            *reinterpret_cast<uint4*>(&Bs[row * 64 + ((kg ^ (row & 7)) << 3)]) = vb;
        }
        __syncthreads();
#pragma unroll
        for (int kk = 0; kk < 2; kk++) {
            short8 af[4], bfr[4];
            int chunk = kk * 4 + hi4;
#pragma unroll
            for (int m = 0; m < 4; m++) {
                int row = wm * 64 + m * 16 + r15;
                U16 u; u.u4 = *reinterpret_cast<const uint4*>(&As[row * 64 + ((chunk ^ (row & 7)) << 3)]);
                af[m] = u.s8;
            }
#pragma unroll
            for (int n = 0; n < 4; n++) {
                int row = wn * 64 + n * 16 + r15;
                U16 u; u.u4 = *reinterpret_cast<const uint4*>(&Bs[row * 64 + ((chunk ^ (row & 7)) << 3)]);
                bfr[n] = u.s8;
            }
#pragma unroll
            for (int m = 0; m < 4; m++)
#pragma unroll
                for (int n = 0; n < 4; n++)
                    acc[m][n] = __builtin_amdgcn_mfma_f32_16x16x32_bf16(af[m], bfr[n], acc[m][n], 0, 0, 0);
        }
        __syncthreads();
    }
#pragma unroll
    for (int m = 0; m < 4; m++)
#pragma unroll
        for (int n = 0; n < 4; n++)
#pragma unroll
            for (int r = 0; r < 4; r++) {
                int gm = wm * 64 + m * 16 + hi4 * 4 + r;
                int gn = n0 + wn * 64 + n * 16 + r15;
                outF[(size_t)ks * (M2P * N2) + (size_t)gm * N2 + gn] = acc[m][n][r];
            }
}

// 512x512x512 square: O = A * BT^T, bf16 out, coalesced rows
__device__ __forceinline__ void sq_job(
        ushort_t* As, ushort_t* Bs,
        const ushort_t* __restrict__ A, const ushort_t* __restrict__ BT,
        ushort_t* __restrict__ O, int local) {
    int m0 = (local >> 2) << 7, n0 = (local & 3) << 7;
    int tid = threadIdx.x;
    int lane = tid & 63, wid = tid >> 6;
    int wm = wid >> 1, wn = wid & 1;
    int r15 = lane & 15, hi4 = lane >> 4;

    f32x4 acc[4][4];
#pragma unroll
    for (int m = 0; m < 4; m++)
#pragma unroll
        for (int n = 0; n < 4; n++) acc[m][n] = (f32x4){0.f, 0.f, 0.f, 0.f};

    for (int kt = 0; kt < 512; kt += 64) {
#pragma unroll
        for (int i = 0; i < 4; i++) {
            int c = tid + i * 256;
            int row = c >> 3, kg = c & 7;
            uint4 va = *reinterpret_cast<const uint4*>(A + (size_t)(m0 + row) * 512 + kt + kg * 8);
            *reinterpret_cast<uint4*>(&As[row * 64 + ((kg ^ (row & 7)) << 3)]) = va;
            uint4 vb = *reinterpret_cast<const uint4*>(BT + (size_t)(n0 + row) * 512 + kt + kg * 8);
            *reinterpret_cast<uint4*>(&Bs[row * 64 + ((kg ^ (row & 7)) << 3)]) = vb;
        }
        __syncthreads();
#pragma unroll
        for (int kk = 0; kk < 2; kk++) {
            short8 af[4], bfr[4];
            int chunk = kk * 4 + hi4;
#pragma unroll
            for (int m = 0; m < 4; m++) {
                int row = wm * 64 + m * 16 + r15;
                U16 u; u.u4 = *reinterpret_cast<const uint4*>(&As[row * 64 + ((chunk ^ (row & 7)) << 3)]);
                af[m] = u.s8;
            }
#pragma unroll
            for (int n = 0; n < 4; n++) {
                int row = wn * 64 + n * 16 + r15;
                U16 u; u.u4 = *reinterpret_cast<const uint4*>(&Bs[row * 64 + ((chunk ^ (row & 7)) << 3)]);
                bfr[n] = u.s8;
            }
#pragma unroll
            for (int m = 0; m < 4; m++)
#pragma unroll
                for (int n = 0; n < 4; n++)
                    acc[m][n] = __builtin_amdgcn_mfma_f32_16x16x32_bf16(af[m], bfr[n], acc[m][n], 0, 0, 0);
        }
        __syncthreads();
    }
#pragma unroll
    for (int m = 0; m < 4; m++)
#pragma unroll
        for (int n = 0; n < 4; n++)
#pragma unroll
            for (int r = 0; r < 4; r++) {
                int gm = m0 + wm * 64 + m * 16 + hi4 * 4 + r;
                int gn = n0 + wn * 64 + n * 16 + r15;
                O[(size_t)gm * 512 + gn] = f2bf(acc[m][n][r]);
            }
}

// --------------------------- fused launch kernels ---------------------------

__global__ __launch_bounds__(256) void g1sq(
        const ushort_t* __restrict__ A1g, const ushort_t* __restrict__ BT1,
        float* __restrict__ part1,
        const ushort_t* __restrict__ Cm, const ushort_t* __restrict__ Dm,
        ushort_t* __restrict__ C2, ushort_t* __restrict__ D2) {
    __shared__ __align__(16) ushort_t As[128 * 64];
    __shared__ __align__(16) ushort_t Bs[128 * 64];
    int bid = blockIdx.x;
    if (bid < 96) { gemm_job(As, Bs, A1g, BT1, bid, 3, 8, K1, KC1, part1); return; }
    int sb = bid - 96;
    if ((sb >> 4) == 0) sq_job(As, Bs, Cm, Dm, C2, sb & 15);
    else                sq_job(As, Bs, Dm, Cm, D2, sb & 15);
}

// gemm2 (72, inline scatter) + C4 (16); zeroes the 8 tail barrier counters.
__global__ __launch_bounds__(256) void g2sq(
        const float* __restrict__ part1, const ushort_t* __restrict__ A2s,
        const ushort_t* __restrict__ WcT, float* __restrict__ part2,
        const ushort_t* __restrict__ C2, const ushort_t* __restrict__ D2,
        ushort_t* __restrict__ C4, uint_t* __restrict__ bar) {
    __shared__ __align__(16) ushort_t As[128 * 64];
    __shared__ __align__(16) ushort_t Bs[128 * 64];
    int bid = blockIdx.x;
    if (bid == 0 && threadIdx.x < 8) bar[threadIdx.x] = 0u;
    if (bid < 72) { gemm2_job(As, Bs, part1, A2s, WcT, bid, part2); return; }
    sq_job(As, Bs, C2, D2, C4, (bid - 72) & 15);
}

// --------------------------- tail megakernel --------------------------------
// 64 blocks x 256 thr. One counter per phase; arrive = RMW, poll = atomic LOAD
// (r12 lesson: RMW-polling convoys to ~37us/barrier).

__device__ __forceinline__ void arrive_wait(uint_t* cnt) {
    __syncthreads();
    __threadfence();
    if (threadIdx.x == 0) {
        __hip_atomic_fetch_add(cnt, 1u, __ATOMIC_ACQ_REL, __HIP_MEMORY_SCOPE_AGENT);
        while (__hip_atomic_load(cnt, __ATOMIC_ACQUIRE, __HIP_MEMORY_SCOPE_AGENT)
               < (uint_t)NBLK_TAIL)
            __builtin_amdgcn_s_sleep(8);
    }
    __syncthreads();
    __threadfence();
}

// per-thread dot of C row-slice with hi+lo vector rows (bf16x8 loads)
__device__ __forceinline__ float dotrow(const ushort_t* __restrict__ Crow,
                                        const ushort_t* __restrict__ Ah,
                                        const ushort_t* __restrict__ Al,
                                        int kin) {
    float acc = 0.f;
    for (int k = 0; k < kin; k += 16) {
        U8x c0, c1, a0, a1, l0, l1;
        c0.u4 = *reinterpret_cast<const uint4*>(Crow + k);
        c1.u4 = *reinterpret_cast<const uint4*>(Crow + k + 8);
        a0.u4 = *reinterpret_cast<const uint4*>(Ah + k);
        a1.u4 = *reinterpret_cast<const uint4*>(Ah + k + 8);
        l0.u4 = *reinterpret_cast<const uint4*>(Al + k);
        l1.u4 = *reinterpret_cast<const uint4*>(Al + k + 8);
#pragma unroll
        for (int j = 0; j < 8; j++)
            acc += bf2f(c0.us[j]) * (bf2f(a0.us[j]) + bf2f(l0.us[j]));
#pragma unroll
        for (int j = 0; j < 8; j++)
            acc += bf2f(c1.us[j]) * (bf2f(a1.us[j]) + bf2f(l1.us[j]));
    }
    return acc;
}

// wave-per-output 512-dot: lane l covers elems [8l, 8l+8); result in lane 0
__device__ __forceinline__ float wavedot512(const ushort_t* __restrict__ Crow,
                                            const ushort_t* __restrict__ Ah,
                                            const ushort_t* __restrict__ Al,
                                            int lane) {
    U8x c, a, l2;
    c.u4  = *reinterpret_cast<const uint4*>(Crow + lane * 8);
    a.u4  = *reinterpret_cast<const uint4*>(Ah + lane * 8);
    l2.u4 = *reinterpret_cast<const uint4*>(Al + lane * 8);
    float s = 0.f;
#pragma unroll
    for (int j = 0; j < 8; j++)
        s += bf2f(c.us[j]) * (bf2f(a.us[j]) + bf2f(l2.us[j]));
    s += __shfl_down(s, 32); s += __shfl_down(s, 16); s += __shfl_down(s, 8);
    s += __shfl_down(s, 4);  s += __shfl_down(s, 2);  s += __shfl_down(s, 1);
    return s;
}

__global__ __launch_bounds__(256) void tailk(
        const float* __restrict__ part2,
        const ushort_t* __restrict__ Cm, const ushort_t* __restrict__ C2,
        const ushort_t* __restrict__ C4,
        ushort_t* __restrict__ Eh, ushort_t* __restrict__ El,
        ushort_t* __restrict__ Fh, ushort_t* __restrict__ Fl,
        ushort_t* __restrict__ Gh, ushort_t* __restrict__ Gl,
        ushort_t* __restrict__ Hh, ushort_t* __restrict__ Hl,
        ushort_t* __restrict__ Wh, ushort_t* __restrict__ Wl,
        float* __restrict__ out, uint_t* __restrict__ bar) {
    int gtid = blockIdx.x * 256 + threadIdx.x;       // < 16384
    int lane = threadIdx.x & 63;
    int wgid = blockIdx.x * 4 + (threadIdx.x >> 6);  // wave id, < 256

    // phase 0: E[v][i] (64 x 256), hi/lo
    {
        float s = 0.f;
#pragma unroll
        for (int ks = 0; ks < KS2; ks++) s += part2[(size_t)ks * (M2P * N2) + gtid];
        ushort_t h = f2bf(s);
        Eh[gtid] = h; El[gtid] = f2bf(s - bf2f(h));
    }
    arrive_wait(&bar[0]);

    // phase F: 32 vouts x 512 n (kin=256, Cp=C)
    {
        int vout = gtid >> 9, n = gtid & 511;
        int b2 = vout >> 3, k2 = vout & 7;
        int Arow = b2 * 16 + 2 * k2;
        float val = dotrow(Cm + (size_t)n * 512, Eh + (size_t)Arow * 256,
                           El + (size_t)Arow * 256, 256);
        if (n < 256)
            val += bf2f(Eh[(size_t)(Arow + 1) * 256 + n]) +
                   bf2f(El[(size_t)(Arow + 1) * 256 + n]);
        ushort_t h = f2bf(val);
        Fh[gtid] = h; Fl[gtid] = f2bf(val - bf2f(h));
    }
    arrive_wait(&bar[1]);

    // phase G: 16 vouts x 512 n (kin=512, Cp=C2)
    if (gtid < 8192) {
        int vout = gtid >> 9, n = gtid & 511;
        int b2 = vout >> 2, k2 = vout & 3;
        int Arow = b2 * 8 + 2 * k2;
        float val = dotrow(C2 + (size_t)n * 512, Fh + (size_t)Arow * 512,
                           Fl + (size_t)Arow * 512, 512);
        val += bf2f(Fh[(size_t)(Arow + 1) * 512 + n]) +
               bf2f(Fl[(size_t)(Arow + 1) * 512 + n]);
        ushort_t h = f2bf(val);
        Gh[gtid] = h; Gl[gtid] = f2bf(val - bf2f(h));
    }
    arrive_wait(&bar[2]);

    // phase H: 8 vouts x 512 n, wave-per-output (Cp=C4)
    for (int o = wgid; o < 4096; o += 256) {
        int vout = o >> 9, n = o & 511;
        int b2 = vout >> 1, k2 = vout & 1;
        int Arow = b2 * 4 + 2 * k2;
        float val = wavedot512(C4 + (size_t)n * 512, Gh + (size_t)Arow * 512,
                               Gl + (size_t)Arow * 512, lane);
        if (lane == 0) {
            val += bf2f(Gh[(size_t)(Arow + 1) * 512 + n]) +
                   bf2f(Gl[(size_t)(Arow + 1) * 512 + n]);
            ushort_t h = f2bf(val);
            Hh[o] = h; Hl[o] = f2bf(val - bf2f(h));
        }
    }
    arrive_wait(&bar[3]);

    // phase W: w_b = C4 * h_{b,0}, 4 x 512, wave-per-output
    for (int o = wgid; o < 2048; o += 256) {
        int b2 = o >> 9, n = o & 511;
        float val = wavedot512(C4 + (size_t)n * 512, Hh + (size_t)(2 * b2) * 512,
                               Hl + (size_t)(2 * b2) * 512, lane);
        if (lane == 0) {
            ushort_t h = f2bf(val);
            Wh[o] = h; Wl[o] = f2bf(val - bf2f(h));
        }
    }
    arrive_wait(&bar[4]);

    // phase Y: y_b[n] = C4[n,:]*w_b + h_{b,1}[n], n<256  (C8*h0 == C4*(C4*h0))
    for (int o = wgid; o < 1024; o += 256) {
        int b2 = o >> 8, n = o & 255;
        float val = wavedot512(C4 + (size_t)n * 512, Wh + (size_t)b2 * 512,
                               Wl + (size_t)b2 * 512, lane);
        if (lane == 0) {
            val += bf2f(Hh[(size_t)(2 * b2 + 1) * 512 + n]) +
                   bf2f(Hl[(size_t)(2 * b2 + 1) * 512 + n]);
            out[b2 * 256 + n] = val;
        }
    }
}

// --------------------------- launch ----------------------------------------

extern "C" void kernel_launch(void* const* d_in, const int* in_sizes, int n_in,
                              void* d_out, int out_size, void* d_ws, size_t ws_size,
                              hipStream_t stream) {
    const float* inputs   = (const float*)d_in[0];
    const float* eig_vals = (const float*)d_in[1];
    const float* eig_vecs = (const float*)d_in[2];
    const float* m_u      = (const float*)d_in[3];
    const float* m_phi    = (const float*)d_in[4];
    const float* m_y      = (const float*)d_in[5];
    float* out = (float*)d_out;
    char* ws = (char*)d_ws;

    ushort_t* A1g   = (ushort_t*)(ws);               // 1572864
    ushort_t* BT1   = (ushort_t*)(ws + 1572864);     // 4194304
    ushort_t* WcT   = (ushort_t*)(ws + 5767168);     // 3538944
    ushort_t* A2s   = (ushort_t*)(ws + 9306112);     // 1769472 (lag cols only)
    float*    part1 = (float*)   (ws + 11075584);    // 6291456
    float*    part2 = (float*)   (ws + 17367040);    // 4718592
    ushort_t* Eh    = (ushort_t*)(ws + 22085632);    // 32768
    ushort_t* El    = (ushort_t*)(ws + 22118400);    // 32768
    ushort_t* Cmat  = (ushort_t*)(ws + 22151168);    // 524288
    ushort_t* Dmat  = (ushort_t*)(ws + 22675456);    // 524288
    ushort_t* C2    = (ushort_t*)(ws + 23199744);    // 524288
    ushort_t* D2    = (ushort_t*)(ws + 23724032);    // 524288
    ushort_t* C4    = (ushort_t*)(ws + 24248320);    // 524288
    ushort_t* Fh    = (ushort_t*)(ws + 24772608);    // 32768
    ushort_t* Fl    = (ushort_t*)(ws + 24805376);    // 32768
    ushort_t* Gh    = (ushort_t*)(ws + 24838144);    // 16384
    ushort_t* Gl    = (ushort_t*)(ws + 24854528);    // 16384
    ushort_t* Hh    = (ushort_t*)(ws + 24870912);    // 8192
    ushort_t* Hl    = (ushort_t*)(ws + 24879104);    // 8192
    ushort_t* Wh    = (ushort_t*)(ws + 24887296);    // 4096
    ushort_t* Wl    = (ushort_t*)(ws + 24891392);    // 4096
    uint_t*   bar   = (uint_t*)  (ws + 24895488);    // 32
                                                     // end 24895520

    hipLaunchKernelGGL(prep, dim3(NB_TOT), dim3(256), 0, stream,
                       inputs, eig_vals, eig_vecs, m_u, m_phi, m_y,
                       A1g, BT1, WcT, A2s, Cmat, Dmat);

    hipLaunchKernelGGL(g1sq, dim3(96 + 32), dim3(256), 0, stream,
                       A1g, BT1, part1, Cmat, Dmat, C2, D2);

    hipLaunchKernelGGL(g2sq, dim3(72 + 16), dim3(256), 0, stream,
                       part1, A2s, WcT, part2, C2, D2, C4, bar);

    hipLaunchKernelGGL(tailk, dim3(NBLK_TAIL), dim3(256), 0, stream,
                       part2, Cmat, C2, C4,
                       Eh, El, Fh, Fl, Gh, Gl, Hh, Hl, Wh, Wl, out, bar);
}

// Round 14
// 111.127 us; speedup vs baseline: 1.7897x; 1.4126x over previous
//
#include <hip/hip_runtime.h>
#include <hip/hip_bf16.h>

// ---------------------------------------------------------------------------
// STU, last P=16 steps. r14: prefix-power structure, NO device barriers
// (r12/r13 lesson: device-wide barrier ~25us on MI355X, never on the path).
// C=[[A1,A2],[I,0]]; C^j top-left 256x256 == G_j;  y_b = sum_j G_j d_{b,15-j}.
// C-chain + D=C^T-chain so every GEMM reads A and BT in natural row layout.
//   L1 prep : builders + C, D + Gstack seeds j=0 (I), j=1 (A1)
//   L2 g1sq : gemm1(96) + C2 (+G2), D2
//   L3 g2r2 : gemm2(72, inline part1-reduce) + C3(+G3), C4(+G4), D3, D4
//   L4 r3red: delta-reduce -> DbigF f32 (64) + C8(+G8), D5,D6,D7 full,
//             C5,C6,C7 G-only (4 blocks each: top-left quarter only)
//   L5 r4   : C9..C15 G-only (7 x 4 blocks), A=C8, BT=D1..D7
//   L6 vfin : out[b][n] = sum_c Gstack[n][c] * DbigF[b][c]  (f32 delta)
// ---------------------------------------------------------------------------

#define L_SEQ   2048
#define D_OUT   256
#define NK      24
#define PTR     16
#define T0      (L_SEQ - PTR)     // 2032
#define M1      (NK * PTR)        // 384
#define N1      1024
#define K1      2048
#define K2      6912
#define M2P     128
#define N2      256
#define KS1     4
#define KC1     512
#define KS2     36
#define KC2     192

#define NB_A1   384
#define NB_BT   512
#define NB_WP   384
#define NB_WM   768
#define NB_LG   192
#define NB_C    1024
#define NB_CT   1024
#define NB_GS   512
#define NB_TOT  (NB_A1+NB_BT+NB_WP+NB_WM+NB_LG+NB_C+NB_CT+NB_GS)

typedef unsigned short ushort_t;
typedef unsigned int   uint_t;
typedef __attribute__((ext_vector_type(8))) short short8;
typedef __attribute__((ext_vector_type(4))) float f32x4;

union U16 { uint4 u4; short8 s8; };
union U8x { uint4 u4; ushort_t us[8]; };

__device__ inline ushort_t f2bf(float f) {
    uint_t x = __float_as_uint(f);
    uint_t r = (x + 0x7fffu + ((x >> 16) & 1u)) >> 16;   // RNE
    return (ushort_t)r;
}
__device__ inline float bf2f(ushort_t u) {
    return __uint_as_float(((uint_t)u) << 16);
}
__device__ inline uint_t pack2bf(float a, float b) {
    return (uint_t)f2bf(a) | ((uint_t)f2bf(b) << 16);
}

// --------------------------- fused prep -------------------------------------

__global__ __launch_bounds__(256) void prep(
        const float* __restrict__ inputs, const float* __restrict__ eig_vals,
        const float* __restrict__ eig_vecs, const float* __restrict__ m_u,
        const float* __restrict__ m_phi, const float* __restrict__ m_y,
        ushort_t* __restrict__ A1g, ushort_t* __restrict__ BT1,
        ushort_t* __restrict__ WcT, ushort_t* __restrict__ A2s,
        ushort_t* __restrict__ Cmat, ushort_t* __restrict__ Dmat,
        ushort_t* __restrict__ Gstack) {
    __shared__ float tile[64][65];
    int bi = blockIdx.x, tid = threadIdx.x;

    if (bi < NB_A1) {
        int idx = bi * 256 + tid;
        int m = idx >> 8, g = idx & 255;
        int k = m >> 4, li = m & 15;
        int t0 = g << 3;
        float sc = sqrtf(sqrtf(eig_vals[k]));
        int sbase = T0 + li - t0;
        U8x v;
#pragma unroll
        for (int j = 0; j < 8; j++) {
            int s = sbase - j;
            float val = (s >= 0) ? sc * eig_vecs[s * NK + k] : 0.f;
            v.us[j] = f2bf(val);
        }
        *reinterpret_cast<uint4*>(A1g + (size_t)m * 2048 + t0) = v.u4;
        return;
    }
    bi -= NB_A1;
    if (bi < NB_BT) {
        int b = bi >> 7, rem = bi & 127;
        int t0 = (rem >> 2) << 6, d0 = (rem & 3) << 6;
#pragma unroll
        for (int i = 0; i < 4; i++) {
            int idx = tid + i * 256;
            int r = idx >> 4, cq = idx & 15;
            float4 v = *reinterpret_cast<const float4*>(
                inputs + ((size_t)b * L_SEQ + t0 + r) * D_OUT + d0 + cq * 4);
            tile[r][cq * 4 + 0] = v.x; tile[r][cq * 4 + 1] = v.y;
            tile[r][cq * 4 + 2] = v.z; tile[r][cq * 4 + 3] = v.w;
        }
        __syncthreads();
        uint_t* dst = reinterpret_cast<uint_t*>(BT1);
#pragma unroll
        for (int i = 0; i < 8; i++) {
            int idx = tid + i * 256;
            int d = idx >> 5, tp = idx & 31;
            uint_t val = pack2bf(tile[2 * tp][d], tile[2 * tp + 1][d]);
            dst[((size_t)(b * 256 + d0 + d)) * (K1 / 2) + (t0 >> 1) + tp] = val;
        }
        return;
    }
    bi -= NB_BT;
    if (bi < NB_WP) {
        int c0 = (bi >> 2) << 6, o0 = (bi & 3) << 6;
#pragma unroll
        for (int i = 0; i < 4; i++) {
            int idx = tid + i * 256;
            int r = idx >> 4, cq = idx & 15;
            float4 v = *reinterpret_cast<const float4*>(
                m_phi + ((size_t)(c0 + r)) * D_OUT + o0 + cq * 4);
            tile[r][cq * 4 + 0] = v.x; tile[r][cq * 4 + 1] = v.y;
            tile[r][cq * 4 + 2] = v.z; tile[r][cq * 4 + 3] = v.w;
        }
        __syncthreads();
        uint_t* dst = reinterpret_cast<uint_t*>(WcT);
#pragma unroll
        for (int i = 0; i < 8; i++) {
            int idx = tid + i * 256;
            int o = idx >> 5, cp = idx & 31;
            uint_t val = pack2bf(tile[2 * cp][o], tile[2 * cp + 1][o]);
            dst[((size_t)(o0 + o)) * (K2 / 2) + (c0 >> 1) + cp] = val;
        }
        return;
    }
    bi -= NB_WP;
    if (bi < NB_WM) {
        int idx = bi * 256 + tid;
        int o = (int)((unsigned)idx / 768u), j = idx - o * 768;
        int kk = j >> 8, i = j & 255;
        WcT[(size_t)o * K2 + 6144 + j] = f2bf(m_u[o * 768 + i * 3 + kk]);
        return;
    }
    bi -= NB_WM;
    if (bi < NB_LG) {
        int idx = bi * 256 + tid;
        int r = (int)((unsigned)idx / 768u), j = idx - r * 768;
        int kk = j >> 8, i = j & 255;
        int b = r >> 4, li = r & 15;
        int l = T0 + li;
        A2s[(size_t)r * K2 + 6144 + j] =
            f2bf(inputs[((size_t)b * L_SEQ + l - kk) * D_OUT + i]);
        return;
    }
    bi -= NB_LG;
    if (bi < NB_C) {
        int idx = bi * 256 + tid;
        int r = idx >> 9, c = idx & 511;
        float val = (r < 256) ? m_y[(size_t)r * 512 + c]
                              : ((c == r - 256) ? 1.f : 0.f);
        Cmat[idx] = f2bf(val);
        return;
    }
    bi -= NB_C;
    if (bi < NB_CT) {
        int idx = bi * 256 + tid;
        int r = idx >> 9, c = idx & 511;
        float val = (c < 256) ? m_y[(size_t)c * 512 + r]
                              : ((r == c - 256) ? 1.f : 0.f);
        Dmat[idx] = f2bf(val);
        return;
    }
    bi -= NB_CT;
    {
        // Gstack seeds: cols 0..255 = G_0 = I, cols 256..511 = G_1 = A1
        int idx = bi * 256 + tid;                // < 131072
        int o = idx >> 9, c = idx & 511;
        float val = (c < 256) ? ((o == c) ? 1.f : 0.f)
                              : m_y[(size_t)o * 512 + (c - 256)];
        Gstack[(size_t)o * 4096 + c] = f2bf(val);
    }
}

// ------------------- shared GEMM bodies (device inline) ---------------------

__device__ __forceinline__ void gemm_job(
        ushort_t* As, ushort_t* Bs,
        const ushort_t* __restrict__ A, const ushort_t* __restrict__ BT,
        int bid, int nm, int nn, int K, int kchunk, float* __restrict__ outF) {
    int ks = bid / (nm * nn);
    int rem = bid - ks * (nm * nn);
    int m0 = (rem / nn) << 7;
    int n0 = (rem % nn) << 7;
    int k0 = ks * kchunk;
    int M = nm << 7, N = nn << 7;
    int tid = threadIdx.x;
    int lane = tid & 63, wid = tid >> 6;
    int wm = wid >> 1, wn = wid & 1;
    int r15 = lane & 15, hi4 = lane >> 4;

    f32x4 acc[4][4];
#pragma unroll
    for (int m = 0; m < 4; m++)
#pragma unroll
        for (int n = 0; n < 4; n++) acc[m][n] = (f32x4){0.f, 0.f, 0.f, 0.f};

    for (int kt = k0; kt < k0 + kchunk; kt += 64) {
#pragma unroll
        for (int i = 0; i < 4; i++) {
            int c = tid + i * 256;
            int row = c >> 3, kg = c & 7;
            uint4 va = *reinterpret_cast<const uint4*>(A + (size_t)(m0 + row) * K + kt + kg * 8);
            *reinterpret_cast<uint4*>(&As[row * 64 + ((kg ^ (row & 7)) << 3)]) = va;
            uint4 vb = *reinterpret_cast<const uint4*>(BT + (size_t)(n0 + row) * K + kt + kg * 8);
            *reinterpret_cast<uint4*>(&Bs[row * 64 + ((kg ^ (row & 7)) << 3)]) = vb;
        }
        __syncthreads();
#pragma unroll
        for (int kk = 0; kk < 2; kk++) {
            short8 af[4], bfr[4];
            int chunk = kk * 4 + hi4;
#pragma unroll
            for (int m = 0; m < 4; m++) {
                int row = wm * 64 + m * 16 + r15;
                U16 u; u.u4 = *reinterpret_cast<const uint4*>(&As[row * 64 + ((chunk ^ (row & 7)) << 3)]);
                af[m] = u.s8;
            }
#pragma unroll
            for (int n = 0; n < 4; n++) {
                int row = wn * 64 + n * 16 + r15;
                U16 u; u.u4 = *reinterpret_cast<const uint4*>(&Bs[row * 64 + ((chunk ^ (row & 7)) << 3)]);
                bfr[n] = u.s8;
            }
#pragma unroll
            for (int m = 0; m < 4; m++)
#pragma unroll
                for (int n = 0; n < 4; n++)
                    acc[m][n] = __builtin_amdgcn_mfma_f32_16x16x32_bf16(af[m], bfr[n], acc[m][n], 0, 0, 0);
        }
        __syncthreads();
    }
#pragma unroll
    for (int m = 0; m < 4; m++)
#pragma unroll
        for (int n = 0; n < 4; n++)
#pragma unroll
            for (int r = 0; r < 4; r++) {
                int gm = m0 + wm * 64 + m * 16 + hi4 * 4 + r;
                int gn = n0 + wn * 64 + n * 16 + r15;
                outF[(size_t)ks * M * N + (size_t)gm * N + gn] = acc[m][n][r];
            }
}

// gemm2 with inline part1-reduce A-staging (validated r13)
__device__ __forceinline__ void gemm2_job(
        ushort_t* As, ushort_t* Bs,
        const float* __restrict__ part1, const ushort_t* __restrict__ A2lag,
        const ushort_t* __restrict__ BT, int bid, float* __restrict__ outF) {
    int ks = bid >> 1;
    int n0 = (bid & 1) << 7;
    int k0 = ks * KC2;
    int tid = threadIdx.x;
    int lane = tid & 63, wid = tid >> 6;
    int wm = wid >> 1, wn = wid & 1;
    int r15 = lane & 15, hi4 = lane >> 4;

    f32x4 acc[4][4];
#pragma unroll
    for (int m = 0; m < 4; m++)
#pragma unroll
        for (int n = 0; n < 4; n++) acc[m][n] = (f32x4){0.f, 0.f, 0.f, 0.f};

    for (int kt = k0; kt < k0 + KC2; kt += 64) {
#pragma unroll
        for (int i = 0; i < 4; i++) {
            int c = tid + i * 256;
            int row = c >> 3, kg = c & 7;
            int col = kt + kg * 8;
            uint4 va;
            if (col < 6144) {
                if (row < 64) {
                    int gm = (col >> 8) * 16 + (row & 15);
                    int gn = ((row >> 4) << 8) + (col & 255);
                    const float* p = part1 + (size_t)gm * 1024 + gn;
                    float4 s0 = *reinterpret_cast<const float4*>(p);
                    float4 s1 = *reinterpret_cast<const float4*>(p + 4);
#pragma unroll
                    for (int q = 1; q < KS1; q++) {
                        const float* pq = p + (size_t)q * (M1 * N1);
                        float4 a0 = *reinterpret_cast<const float4*>(pq);
                        float4 a1 = *reinterpret_cast<const float4*>(pq + 4);
                        s0.x += a0.x; s0.y += a0.y; s0.z += a0.z; s0.w += a0.w;
                        s1.x += a1.x; s1.y += a1.y; s1.z += a1.z; s1.w += a1.w;
                    }
                    va.x = pack2bf(s0.x, s0.y); va.y = pack2bf(s0.z, s0.w);
                    va.z = pack2bf(s1.x, s1.y); va.w = pack2bf(s1.z, s1.w);
                } else {
                    va.x = 0u; va.y = 0u; va.z = 0u; va.w = 0u;
                }
            } else {
                va = *reinterpret_cast<const uint4*>(A2lag + (size_t)row * K2 + col);
            }
            *reinterpret_cast<uint4*>(&As[row * 64 + ((kg ^ (row & 7)) << 3)]) = va;
            uint4 vb = *reinterpret_cast<const uint4*>(BT + (size_t)(n0 + row) * K2 + kt + kg * 8);
            *reinterpret_cast<uint4*>(&Bs[row * 64 + ((kg ^ (row & 7)) << 3)]) = vb;
        }
        __syncthreads();
#pragma unroll
        for (int kk = 0; kk < 2; kk++) {
            short8 af[4], bfr[4];
            int chunk = kk * 4 + hi4;
#pragma unroll
            for (int m = 0; m < 4; m++) {
                int row = wm * 64 + m * 16 + r15;
                U16 u; u.u4 = *reinterpret_cast<const uint4*>(&As[row * 64 + ((chunk ^ (row & 7)) << 3)]);
                af[m] = u.s8;
            }
#pragma unroll
            for (int n = 0; n < 4; n++) {
                int row = wn * 64 + n * 16 + r15;
                U16 u; u.u4 = *reinterpret_cast<const uint4*>(&Bs[row * 64 + ((chunk ^ (row & 7)) << 3)]);
                bfr[n] = u.s8;
            }
#pragma unroll
            for (int m = 0; m < 4; m++)
#pragma unroll
                for (int n = 0; n < 4; n++)
                    acc[m][n] = __builtin_amdgcn_mfma_f32_16x16x32_bf16(af[m], bfr[n], acc[m][n], 0, 0, 0);
        }
        __syncthreads();
    }
#pragma unroll
    for (int m = 0; m < 4; m++)
#pragma unroll
        for (int n = 0; n < 4; n++)
#pragma unroll
            for (int r = 0; r < 4; r++) {
                int gm = wm * 64 + m * 16 + hi4 * 4 + r;
                int gn = n0 + wn * 64 + n * 16 + r15;
                outF[(size_t)ks * (M2P * N2) + (size_t)gm * N2 + gn] = acc[m][n][r];
            }
}

// 512x512x512 product: O = A * BT^T (bf16, natural rows).
// O may be null (G-only); Gst: write top-left 256x256 into Gstack[:, jbase*256+:].
__device__ __forceinline__ void sq_job(
        ushort_t* As, ushort_t* Bs,
        const ushort_t* __restrict__ A, const ushort_t* __restrict__ BT,
        ushort_t* __restrict__ O, int local,
        ushort_t* __restrict__ Gst, int jbase) {
    int m0 = (local >> 2) << 7, n0 = (local & 3) << 7;
    int tid = threadIdx.x;
    int lane = tid & 63, wid = tid >> 6;
    int wm = wid >> 1, wn = wid & 1;
    int r15 = lane & 15, hi4 = lane >> 4;

    f32x4 acc[4][4];
#pragma unroll
    for (int m = 0; m < 4; m++)
#pragma unroll
        for (int n = 0; n < 4; n++) acc[m][n] = (f32x4){0.f, 0.f, 0.f, 0.f};

    for (int kt = 0; kt < 512; kt += 64) {
#pragma unroll
        for (int i = 0; i < 4; i++) {
            int c = tid + i * 256;
            int row = c >> 3, kg = c & 7;
            uint4 va = *reinterpret_cast<const uint4*>(A + (size_t)(m0 + row) * 512 + kt + kg * 8);
            *reinterpret_cast<uint4*>(&As[row * 64 + ((kg ^ (row & 7)) << 3)]) = va;
            uint4 vb = *reinterpret_cast<const uint4*>(BT + (size_t)(n0 + row) * 512 + kt + kg * 8);
            *reinterpret_cast<uint4*>(&Bs[row * 64 + ((kg ^ (row & 7)) << 3)]) = vb;
        }
        __syncthreads();
#pragma unroll
        for (int kk = 0; kk < 2; kk++) {
            short8 af[4], bfr[4];
            int chunk = kk * 4 + hi4;
#pragma unroll
            for (int m = 0; m < 4; m++) {
                int row = wm * 64 + m * 16 + r15;
                U16 u; u.u4 = *reinterpret_cast<const uint4*>(&As[row * 64 + ((chunk ^ (row & 7)) << 3)]);
                af[m] = u.s8;
            }
#pragma unroll
            for (int n = 0; n < 4; n++) {
                int row = wn * 64 + n * 16 + r15;
                U16 u; u.u4 = *reinterpret_cast<const uint4*>(&Bs[row * 64 + ((chunk ^ (row & 7)) << 3)]);
                bfr[n] = u.s8;
            }
#pragma unroll
            for (int m = 0; m < 4; m++)
#pragma unroll
                for (int n = 0; n < 4; n++)
                    acc[m][n] = __builtin_amdgcn_mfma_f32_16x16x32_bf16(af[m], bfr[n], acc[m][n], 0, 0, 0);
        }
        __syncthreads();
    }
#pragma unroll
    for (int m = 0; m < 4; m++)
#pragma unroll
        for (int n = 0; n < 4; n++)
#pragma unroll
            for (int r = 0; r < 4; r++) {
                int gm = m0 + wm * 64 + m * 16 + hi4 * 4 + r;
                int gn = n0 + wn * 64 + n * 16 + r15;
                ushort_t h = f2bf(acc[m][n][r]);
                if (O) O[(size_t)gm * 512 + gn] = h;
                if (Gst && gm < 256 && gn < 256)
                    Gst[(size_t)gm * 4096 + jbase * 256 + gn] = h;
            }
}

// --------------------------- fused launch kernels ---------------------------

// L2: gemm1(96) + C2 (full+G2), D2
__global__ __launch_bounds__(256) void g1sq(
        const ushort_t* __restrict__ A1g, const ushort_t* __restrict__ BT1,
        float* __restrict__ part1,
        const ushort_t* __restrict__ Cm, const ushort_t* __restrict__ Dm,
        ushort_t* __restrict__ C2, ushort_t* __restrict__ D2,
        ushort_t* __restrict__ Gst) {
    __shared__ __align__(16) ushort_t As[128 * 64];
    __shared__ __align__(16) ushort_t Bs[128 * 64];
    int bid = blockIdx.x;
    if (bid < 96) { gemm_job(As, Bs, A1g, BT1, bid, 3, 8, K1, KC1, part1); return; }
    int sb = bid - 96;
    if ((sb >> 4) == 0) sq_job(As, Bs, Cm, Dm, C2, sb & 15, Gst, 2);
    else                sq_job(As, Bs, Dm, Cm, D2, sb & 15, (ushort_t*)nullptr, 0);
}

// L3: gemm2(72) + C3(+G3), C4(+G4), D3, D4
__global__ __launch_bounds__(256) void g2r2(
        const float* __restrict__ part1, const ushort_t* __restrict__ A2s,
        const ushort_t* __restrict__ WcT, float* __restrict__ part2,
        const ushort_t* __restrict__ Cm, const ushort_t* __restrict__ Dm,
        const ushort_t* __restrict__ C2, const ushort_t* __restrict__ D2,
        ushort_t* __restrict__ C3, ushort_t* __restrict__ C4,
        ushort_t* __restrict__ D3, ushort_t* __restrict__ D4,
        ushort_t* __restrict__ Gst) {
    __shared__ __align__(16) ushort_t As[128 * 64];
    __shared__ __align__(16) ushort_t Bs[128 * 64];
    int bid = blockIdx.x;
    if (bid < 72) { gemm2_job(As, Bs, part1, A2s, WcT, bid, part2); return; }
    int sb = bid - 72;
    int job = sb >> 4, local = sb & 15;
    if (job == 0)      sq_job(As, Bs, C2, Dm, C3, local, Gst, 3);
    else if (job == 1) sq_job(As, Bs, C2, D2, C4, local, Gst, 4);
    else if (job == 2) sq_job(As, Bs, D2, Cm, D3, local, (ushort_t*)nullptr, 0);
    else               sq_job(As, Bs, D2, C2, D4, local, (ushort_t*)nullptr, 0);
}

// L4: delta-reduce(64) + C8(+G8), D5, D6, D7 full + C5,C6,C7 G-only (4 each)
__global__ __launch_bounds__(256) void r3red(
        const float* __restrict__ part2, float* __restrict__ DbigF,
        const ushort_t* __restrict__ Cm, const ushort_t* __restrict__ Dm,
        const ushort_t* __restrict__ C2, const ushort_t* __restrict__ D2,
        const ushort_t* __restrict__ C3, const ushort_t* __restrict__ D3,
        const ushort_t* __restrict__ C4, const ushort_t* __restrict__ D4,
        ushort_t* __restrict__ C8,
        ushort_t* __restrict__ D5, ushort_t* __restrict__ D6,
        ushort_t* __restrict__ D7, ushort_t* __restrict__ Gst) {
    __shared__ __align__(16) ushort_t As[128 * 64];
    __shared__ __align__(16) ushort_t Bs[128 * 64];
    int bid = blockIdx.x, tid = threadIdx.x;
    if (bid < 64) {
        // DbigF[b][j*256+i] = sum_ks part2[ks][(b*16 + 15-j)*256 + i]
        int idx = bid * 256 + tid;               // < 16384
        int b = idx >> 12, col = idx & 4095;
        int j = col >> 8, i = col & 255;
        int row = b * PTR + (15 - j);
        float s = 0.f;
#pragma unroll
        for (int ks = 0; ks < KS2; ks++)
            s += part2[(size_t)ks * (M2P * N2) + (size_t)row * N2 + i];
        DbigF[idx] = s;
        return;
    }
    int sb = bid - 64;
    if (sb < 16) { sq_job(As, Bs, C4, D4, C8, sb, Gst, 8); return; }
    sb -= 16;
    if (sb < 48) {
        int job = sb >> 4, local = sb & 15;
        if (job == 0)      sq_job(As, Bs, D4, Cm, D5, local, (ushort_t*)nullptr, 0);
        else if (job == 1) sq_job(As, Bs, D4, C2, D6, local, (ushort_t*)nullptr, 0);
        else               sq_job(As, Bs, D4, C3, D7, local, (ushort_t*)nullptr, 0);
        return;
    }
    sb -= 48;                                    // 12 blocks: C5,C6,C7 G-only
    {
        static const int lmap[4] = {0, 1, 4, 5};
        int job = sb >> 2, local = lmap[sb & 3];
        if (job == 0)      sq_job(As, Bs, C4, Dm, (ushort_t*)nullptr, local, Gst, 5);
        else if (job == 1) sq_job(As, Bs, C4, D2, (ushort_t*)nullptr, local, Gst, 6);
        else               sq_job(As, Bs, C4, D3, (ushort_t*)nullptr, local, Gst, 7);
    }
}

// L5: C9..C15 G-only (7 x 4 blocks), A = C8, BT = D1..D7
__global__ __launch_bounds__(256) void r4(
        const ushort_t* __restrict__ C8,
        const ushort_t* __restrict__ Dm, const ushort_t* __restrict__ D2,
        const ushort_t* __restrict__ D3, const ushort_t* __restrict__ D4,
        const ushort_t* __restrict__ D5, const ushort_t* __restrict__ D6,
        const ushort_t* __restrict__ D7, ushort_t* __restrict__ Gst) {
    __shared__ __align__(16) ushort_t As[128 * 64];
    __shared__ __align__(16) ushort_t Bs[128 * 64];
    static const int lmap[4] = {0, 1, 4, 5};
    int bid = blockIdx.x;
    int p = bid >> 2, local = lmap[bid & 3];
    const ushort_t* BT = (p == 0) ? Dm : (p == 1) ? D2 : (p == 2) ? D3 :
                         (p == 3) ? D4 : (p == 4) ? D5 : (p == 5) ? D6 : D7;
    sq_job(As, Bs, C8, BT, (ushort_t*)nullptr, local, Gst, 9 + p);
}

// L6: out[b][n] = sum_c Gstack[n][c] * DbigF[b][c]   (wave per n, 4 batches)
__global__ __launch_bounds__(256) void vfin(
        const ushort_t* __restrict__ Gst, const float* __restrict__ DbigF,
        float* __restrict__ out) {
    int tid = threadIdx.x;
    int lane = tid & 63;
    int n = blockIdx.x * 4 + (tid >> 6);         // 0..255
    const ushort_t* Grow = Gst + (size_t)n * 4096;
    float a0 = 0.f, a1 = 0.f, a2 = 0.f, a3 = 0.f;
#pragma unroll
    for (int it = 0; it < 8; ++it) {
        int c = it * 512 + lane * 8;
        U8x g; g.u4 = *reinterpret_cast<const uint4*>(Grow + c);
        float gv[8];
#pragma unroll
        for (int j = 0; j < 8; j++) gv[j] = bf2f(g.us[j]);
#pragma unroll
        for (int b = 0; b < 4; b++) {
            const float* dp = DbigF + b * 4096 + c;
            float4 d0 = *reinterpret_cast<const float4*>(dp);
            float4 d1 = *reinterpret_cast<const float4*>(dp + 4);
            float s = gv[0] * d0.x + gv[1] * d0.y + gv[2] * d0.z + gv[3] * d0.w
                    + gv[4] * d1.x + gv[5] * d1.y + gv[6] * d1.z + gv[7] * d1.w;
            if (b == 0) a0 += s; else if (b == 1) a1 += s;
            else if (b == 2) a2 += s; else a3 += s;
        }
    }
#pragma unroll
    for (int off = 32; off >= 1; off >>= 1) {
        a0 += __shfl_down(a0, off);
        a1 += __shfl_down(a1, off);
        a2 += __shfl_down(a2, off);
        a3 += __shfl_down(a3, off);
    }
    if (lane == 0) {
        out[0 * 256 + n] = a0;
        out[1 * 256 + n] = a1;
        out[2 * 256 + n] = a2;
        out[3 * 256 + n] = a3;
    }
}

// --------------------------- launch ----------------------------------------

extern "C" void kernel_launch(void* const* d_in, const int* in_sizes, int n_in,
                              void* d_out, int out_size, void* d_ws, size_t ws_size,
                              hipStream_t stream) {
    const float* inputs   = (const float*)d_in[0];
    const float* eig_vals = (const float*)d_in[1];
    const float* eig_vecs = (const float*)d_in[2];
    const float* m_u      = (const float*)d_in[3];
    const float* m_phi    = (const float*)d_in[4];
    const float* m_y      = (const float*)d_in[5];
    float* out = (float*)d_out;
    char* ws = (char*)d_ws;

    ushort_t* A1g    = (ushort_t*)(ws);               // 1572864
    ushort_t* BT1    = (ushort_t*)(ws + 1572864);     // 4194304
    ushort_t* WcT    = (ushort_t*)(ws + 5767168);     // 3538944
    ushort_t* A2s    = (ushort_t*)(ws + 9306112);     // 1769472
    float*    part1  = (float*)   (ws + 11075584);    // 6291456
    float*    part2  = (float*)   (ws + 17367040);    // 4718592
    ushort_t* Cmat   = (ushort_t*)(ws + 22085632);    // 524288
    ushort_t* Dmat   = (ushort_t*)(ws + 22609920);    // 524288
    ushort_t* C2     = (ushort_t*)(ws + 23134208);    // 524288
    ushort_t* D2     = (ushort_t*)(ws + 23658496);    // 524288
    ushort_t* C3     = (ushort_t*)(ws + 24182784);    // 524288
    ushort_t* D3     = (ushort_t*)(ws + 24707072);    // 524288
    ushort_t* C4     = (ushort_t*)(ws + 25231360);    // 524288
    ushort_t* D4     = (ushort_t*)(ws + 25755648);    // 524288
    ushort_t* C8     = (ushort_t*)(ws + 26279936);    // 524288
    ushort_t* D5     = (ushort_t*)(ws + 26804224);    // 524288
    ushort_t* D6     = (ushort_t*)(ws + 27328512);    // 524288
    ushort_t* D7     = (ushort_t*)(ws + 27852800);    // 524288
    ushort_t* Gstack = (ushort_t*)(ws + 28377088);    // 2097152
    float*    DbigF  = (float*)   (ws + 30474240);    // 65536
                                                      // end 30539776

    hipLaunchKernelGGL(prep, dim3(NB_TOT), dim3(256), 0, stream,
                       inputs, eig_vals, eig_vecs, m_u, m_phi, m_y,
                       A1g, BT1, WcT, A2s, Cmat, Dmat, Gstack);

    hipLaunchKernelGGL(g1sq, dim3(96 + 32), dim3(256), 0, stream,
                       A1g, BT1, part1, Cmat, Dmat, C2, D2, Gstack);

    hipLaunchKernelGGL(g2r2, dim3(72 + 64), dim3(256), 0, stream,
                       part1, A2s, WcT, part2, Cmat, Dmat, C2, D2,
                       C3, C4, D3, D4, Gstack);

    hipLaunchKernelGGL(r3red, dim3(64 + 16 + 48 + 12), dim3(256), 0, stream,
                       part2, DbigF, Cmat, Dmat, C2, D2, C3, D3, C4, D4,
                       C8, D5, D6, D7, Gstack);

    hipLaunchKernelGGL(r4, dim3(28), dim3(256), 0, stream,
                       C8, Dmat, D2, D3, D4, D5, D6, D7, Gstack);

    hipLaunchKernelGGL(vfin, dim3(64), dim3(256), 0, stream,
                       Gstack, DbigF, out);
}